// Round 8
// baseline (78.875 us; speedup 1.0000x reference)
//
#include <hip/hip_runtime.h>
#include <hip/hip_bf16.h>

#define CH 384
#define HH 56
#define WW 56
#define HW (HH*WW)      // 3136 = 28*112
#define NN 16
#define BN 112          // pw pix-tile (3136 = 28*112 exact)
#define BK 64           // pw k-chunk
#define CHH 192         // dw ci-half

typedef __attribute__((ext_vector_type(4))) float f32x4;
typedef __attribute__((ext_vector_type(8))) short bf16x8;

// Prepared weights
__device__ float          g_wdw_eff[CH * 9];   // depthwise: u*mx exact fp32, [o][tap]
__device__ __hip_bfloat16 g_wpw_u[CH * CH];    // pointwise: ternary u exact bf16, [co][ci]
__device__ float          g_mx_pw;             // pointwise scale (epilogue multiply)

// ---------- prep stage A: deterministic per-block |w| partial sums ----------
__global__ __launch_bounds__(256) void partial_kernel(const float* __restrict__ wpw,
                                                      double* __restrict__ part) {
    const int t = threadIdx.x;
    const int base = blockIdx.x * 1536;
    double s = 0.0;
    #pragma unroll
    for (int k = 0; k < 6; ++k) s += (double)fabsf(wpw[base + t + k * 256]);
    #pragma unroll
    for (int off = 32; off > 0; off >>= 1) s += __shfl_down(s, off, 64);
    __shared__ double sred[4];
    if ((t & 63) == 0) sred[t >> 6] = s;
    __syncthreads();
    if (t == 0) part[blockIdx.x] = ((sred[0] + sred[1]) + sred[2]) + sred[3];
}

// ---------- prep stage B: finalize scale (in-order, deterministic) + quantize ----------
__global__ __launch_bounds__(512) void quant_kernel(const float* __restrict__ wdw,
                                                    const float* __restrict__ wpw,
                                                    const double* __restrict__ part) {
    const int t = threadIdx.x;
    __shared__ double pl[96];
    __shared__ float s_scale, s_mx;
    if (t < 96) pl[t] = part[t];
    __syncthreads();
    if (t == 0) {
        double tot = 0.0;
        #pragma unroll
        for (int i = 0; i < 96; ++i) tot += pl[i];   // fixed order
        const float mean = (float)(tot / (double)(CH * CH));
        const float mx   = fmaxf(mean, 1e-5f);
        s_mx = mx;
        s_scale = 1.0f / mx;
    }
    __syncthreads();
    const float scale = s_scale;

    const int base = blockIdx.x * 4096 + t * 8;      // 36*512*8 = 147456 exact
    const float4 a = *reinterpret_cast<const float4*>(wpw + base);
    const float4 b = *reinterpret_cast<const float4*>(wpw + base + 4);
    const float vin[8] = {a.x, a.y, a.z, a.w, b.x, b.y, b.z, b.w};
    bf16x8 uo;
    #pragma unroll
    for (int k = 0; k < 8; ++k) {
        float u = rintf(vin[k] * scale);             // jnp.round == RNE
        u = fminf(1.f, fmaxf(-1.f, u));
        __hip_bfloat16 h = __float2bfloat16(u);      // {-1,0,1} exact in bf16
        uo[k] = *reinterpret_cast<short*>(&h);
    }
    *reinterpret_cast<bf16x8*>(g_wpw_u + base) = uo;

    if (blockIdx.x == 0) {
        if (t == 0) g_mx_pw = s_mx;
        if (t < CH) {
            const float* w = wdw + t * 9;
            float asum = 0.f;
            #pragma unroll
            for (int k = 0; k < 9; ++k) asum += fabsf(w[k]);
            const float mxd = fmaxf(asum / 9.0f, 1e-5f);
            const float scd = 1.0f / mxd;
            #pragma unroll
            for (int k = 0; k < 9; ++k) {
                float u = rintf(w[k] * scd);
                u = fminf(1.f, fmaxf(-1.f, u));
                g_wdw_eff[t * 9 + k] = u * mxd;      // exact product
            }
        }
    }
}

// ---------- kernel 1: depthwise; 448 thr, 3 fixed units/thread, full unroll ----------
// Block = (n, h, ci-half): 192 ch of one row. 1344 units = 448*3 exact -> the
// whole load batch (18 float4 + 18 edge scalars) is issued as one independent
// group (round 7: 5.25 variable-trip iterations kept VGPR=36 and serialized
// every iteration on L2 latency). launch_bounds(448,4) = 128-VGPR budget.
__global__ __launch_bounds__(448, 4) void dw_kernel(const float* __restrict__ x,
                                                    __hip_bfloat16* __restrict__ y) {
    __shared__ __attribute__((aligned(16))) __hip_bfloat16 ylds[WW * CHH]; // 21504 B

    const int bid  = blockIdx.x;
    const int orig = (bid & 7) * 224 + (bid >> 3);   // XCD swizzle, 1792 = 8*224
    const int n    = orig / 112;
    const int r    = orig % 112;
    const int h    = r >> 1;
    const int ci0  = (r & 1) * CHH;
    const float* xn = x + (size_t)n * CH * HW;
    const bool r0ok = (h > 0), r2ok = (h < HH - 1);  // block-uniform row pad

    #pragma unroll
    for (int k = 0; k < 3; ++k) {
        const int u   = threadIdx.x + 448 * k;        // 0..1343
        const int cil = u / 7;                        // local ci 0..191
        const int wc  = u % 7;
        const int w0  = wc * 8;
        const int ci  = ci0 + cil;
        const float* xp = xn + (size_t)ci * HW;
        const float* wd = g_wdw_eff + ci * 9;
        float acc[8] = {0.f, 0.f, 0.f, 0.f, 0.f, 0.f, 0.f, 0.f};
        #pragma unroll
        for (int dy = -1; dy <= 1; ++dy) {
            if (dy == -1 && !r0ok) continue;          // zero pad rows (uniform)
            if (dy ==  1 && !r2ok) continue;
            const float* row = xp + (h + dy) * WW;
            const float4 va = *reinterpret_cast<const float4*>(row + w0);
            const float4 vb = *reinterpret_cast<const float4*>(row + w0 + 4);
            const float left  = (w0 > 0)      ? row[w0 - 1] : 0.f;
            const float right = (w0 + 8 < WW) ? row[w0 + 8] : 0.f;
            const float xv[10] = {left, va.x, va.y, va.z, va.w,
                                  vb.x, vb.y, vb.z, vb.w, right};
            #pragma unroll
            for (int dx = 0; dx < 3; ++dx) {
                const float wv = wd[(dy + 1) * 3 + dx];
                #pragma unroll
                for (int j = 0; j < 8; ++j) acc[j] += xv[j + dx] * wv;
            }
        }
        // transposed store, swizzled: row = w0+j (row&7==j, row>>3==wc)
        #pragma unroll
        for (int j = 0; j < 8; ++j)
            ylds[(w0 + j) * CHH + (cil ^ ((j ^ wc) << 3))] = __float2bfloat16(acc[j]);
    }
    __syncthreads();

    // ---- coalesced dump: y global LINEAR [pix][ci] (pitch CH), un-swizzle ----
    __hip_bfloat16* yb = y + ((size_t)n * HW + (size_t)h * WW) * CH + ci0;
    #pragma unroll
    for (int k = 0; k < 3; ++k) {
        const int s  = threadIdx.x + 448 * k;         // 0..1343
        const int e  = s * 8;
        const int w  = e / CHH;
        const int c  = e - w * CHH;
        const int sw = ((w & 7) ^ ((w >> 3) & 7)) << 3;
        *reinterpret_cast<bf16x8*>(yb + (size_t)w * CH + c) =
            *reinterpret_cast<const bf16x8*>(&ylds[w * CHH + (c ^ sw)]);
    }
}

// ---------- kernel 2: pointwise GEMM, global_load_lds-staged B, dbuf ----------
// (unchanged — no longer in the top-5 dispatches)
#define STAGE(B, KC) do {                                                         \
    const int _k0 = (KC) * BK;                                                    \
    _Pragma("unroll")                                                             \
    for (int _i = 0; _i < 4; ++_i) {                                              \
        const int _sb = wv * 4 + _i;                                              \
        if (_sb < 14) {                                                           \
            const int _s  = _sb * 64 + lane;                                      \
            const int _p  = _s >> 3;                                              \
            const int _c8 = (_s & 7) ^ (_p & 7);                                  \
            __builtin_amdgcn_global_load_lds(                                     \
                (const __attribute__((address_space(1))) void*)                  \
                    (yb + (size_t)_p * CH + _k0 + _c8 * 8),                       \
                (__attribute__((address_space(3))) void*)                        \
                    (&blds[(B)][0] + _sb * 512),                                  \
                16, 0, 0);                                                        \
        }                                                                         \
    }                                                                             \
} while (0)

#define LOADA(dst, KC) {                                                          \
    dst[0][0] = *reinterpret_cast<const bf16x8*>(ap0 + (KC) * 64);                \
    dst[0][1] = *reinterpret_cast<const bf16x8*>(ap0 + (KC) * 64 + 32);           \
    dst[1][0] = *reinterpret_cast<const bf16x8*>(ap1 + (KC) * 64);                \
    dst[1][1] = *reinterpret_cast<const bf16x8*>(ap1 + (KC) * 64 + 32); }

__global__ __launch_bounds__(256) void pw_kernel(const __hip_bfloat16* __restrict__ y,
                                                 float* __restrict__ out) {
    __shared__ __attribute__((aligned(16))) __hip_bfloat16 blds[2][BN * BK]; // 2x14336 B

    const int bid  = blockIdx.x;
    const int orig = (bid & 7) * 168 + (bid >> 3);   // XCD swizzle, 1344 = 8*168
    const int n  = orig / 84;                        // 84 = 28*3
    const int r  = orig % 84;
    const int pt = r / 3;                            // pix tile 0..27
    const int cb = r % 3;                            // co tile 0..2
    const int wv   = threadIdx.x >> 6;
    const int lane = threadIdx.x & 63;
    const int lr   = lane & 15;
    const int lk   = lane >> 4;

    const __hip_bfloat16* yb = y + ((size_t)n * HW + (size_t)pt * BN) * CH;
    const __hip_bfloat16* ap0 = g_wpw_u + (size_t)(cb * 128 + wv * 32 + lr) * CH + 8 * lk;
    const __hip_bfloat16* ap1 = ap0 + (size_t)16 * CH;

    f32x4 acc[2][7];
    #pragma unroll
    for (int i = 0; i < 2; ++i)
        #pragma unroll
        for (int j = 0; j < 7; ++j) acc[i][j] = (f32x4){0.f, 0.f, 0.f, 0.f};

    bf16x8 areg[2][2][2];                            // [buf][cofrag][kk]
    STAGE(0, 0);
    LOADA(areg[0], 0);
    __syncthreads();                                 // stage(0) + A(0) complete

    #pragma unroll
    for (int kc = 0; kc < 6; ++kc) {
        const int cur = kc & 1;
        if (kc < 5) { STAGE(cur ^ 1, kc + 1); LOADA(areg[cur ^ 1], kc + 1); }
        #pragma unroll
        for (int kk = 0; kk < 2; ++kk) {
            bf16x8 bfr[7];
            #pragma unroll
            for (int j = 0; j < 7; ++j) {
                const int p  = 16 * j + lr;
                const int c8 = (kk * 4 + lk) ^ (p & 7);
                bfr[j] = *reinterpret_cast<const bf16x8*>(&blds[cur][p * 64 + c8 * 8]);
            }
            #pragma unroll
            for (int i = 0; i < 2; ++i)
                #pragma unroll
                for (int j = 0; j < 7; ++j)
                    acc[i][j] = __builtin_amdgcn_mfma_f32_16x16x32_bf16(
                        areg[cur][i][kk], bfr[j], acc[i][j], 0, 0, 0);
        }
        __syncthreads();   // drains next-chunk stage (vmcnt0) + guards dbuf reuse
    }

    // epilogue: D col(lane&15)=pix, row(lk*4+reg)=co
    const float s = g_mx_pw;
    float* ob = out + (size_t)n * CH * HW + (size_t)pt * BN;
    #pragma unroll
    for (int i = 0; i < 2; ++i) {
        const int co0 = cb * 128 + wv * 32 + i * 16 + lk * 4;
        #pragma unroll
        for (int j = 0; j < 7; ++j) {
            const int px = 16 * j + lr;
            #pragma unroll
            for (int rr = 0; rr < 4; ++rr)
                ob[(size_t)(co0 + rr) * HW + px] = acc[i][j][rr] * s;
        }
    }
}

// ---------- fallback: fused kernel (only if ws too small) ----------
__global__ __launch_bounds__(512) void fused_kernel(const float* __restrict__ x,
                                                    float* __restrict__ out) {
    __shared__ __attribute__((aligned(16))) __hip_bfloat16 ylds[64 * CH];
    const int bid  = blockIdx.x;
    const int orig = (bid & 7) * 112 + (bid >> 3);
    const int n = orig / HH, h = orig % HH;
    const float* xn = x + (size_t)n * CH * HW;

    for (int u = threadIdx.x; u < CH * 7; u += 512) {
        const int ci = u / 7;
        const int wc = u % 7;
        const int w0 = wc * 8;
        const float* xp = xn + (size_t)ci * HW;
        const float* wd = g_wdw_eff + ci * 9;
        float acc[8] = {0.f, 0.f, 0.f, 0.f, 0.f, 0.f, 0.f, 0.f};
        #pragma unroll
        for (int dy = -1; dy <= 1; ++dy) {
            const int hh = h + dy;
            if (hh < 0 || hh >= HH) continue;
            const float* row = xp + hh * WW;
            const float4 va = *reinterpret_cast<const float4*>(row + w0);
            const float4 vb = *reinterpret_cast<const float4*>(row + w0 + 4);
            const float left  = (w0 > 0)      ? row[w0 - 1] : 0.f;
            const float right = (w0 + 8 < WW) ? row[w0 + 8] : 0.f;
            const float xv[10] = {left, va.x, va.y, va.z, va.w,
                                  vb.x, vb.y, vb.z, vb.w, right};
            #pragma unroll
            for (int dx = 0; dx < 3; ++dx) {
                const float wvv = wd[(dy + 1) * 3 + dx];
                #pragma unroll
                for (int j = 0; j < 8; ++j) acc[j] += xv[j + dx] * wvv;
            }
        }
        #pragma unroll
        for (int j = 0; j < 8; ++j)
            ylds[(w0 + j) * CH + (ci ^ ((j ^ wc) << 3))] = __float2bfloat16(acc[j]);
    }
    __syncthreads();

    const int wv   = threadIdx.x >> 6;
    const int lane = threadIdx.x & 63;
    const int lr   = lane & 15;
    const int lk   = lane >> 4;
    f32x4 acc[3][4];
    #pragma unroll
    for (int i = 0; i < 3; ++i)
        #pragma unroll
        for (int j = 0; j < 4; ++j) acc[i][j] = (f32x4){0.f, 0.f, 0.f, 0.f};
    const __hip_bfloat16* abase = g_wpw_u + (size_t)(wv * 16 + lr) * CH + 8 * lk;
    for (int k0 = 0; k0 < CH; k0 += 32) {
        bf16x8 bfr[4];
        #pragma unroll
        for (int j = 0; j < 4; ++j) {
            const int row = 16 * j + lr;
            const int sw  = ((row & 7) ^ ((row >> 3) & 7)) << 3;
            bfr[j] = *reinterpret_cast<const bf16x8*>(&ylds[row * CH + ((k0 + 8 * lk) ^ sw)]);
        }
        #pragma unroll
        for (int i = 0; i < 3; ++i) {
            const bf16x8 afr = *reinterpret_cast<const bf16x8*>(abase + (size_t)(i * 128) * CH + k0);
            #pragma unroll
            for (int j = 0; j < 4; ++j)
                acc[i][j] = __builtin_amdgcn_mfma_f32_16x16x32_bf16(afr, bfr[j], acc[i][j], 0, 0, 0);
        }
    }
    const float s = g_mx_pw;
    float* obase = out + (size_t)n * CH * HW + (size_t)h * WW;
    #pragma unroll
    for (int j = 0; j < 4; ++j) {
        const int pix = 16 * j + lr;
        if (pix >= WW) continue;
        #pragma unroll
        for (int i = 0; i < 3; ++i) {
            const int co0 = (wv + 8 * i) * 16 + lk * 4;
            #pragma unroll
            for (int rr = 0; rr < 4; ++rr)
                obase[(size_t)(co0 + rr) * HW + pix] = acc[i][j][rr] * s;
        }
    }
}

extern "C" void kernel_launch(void* const* d_in, const int* in_sizes, int n_in,
                              void* d_out, int out_size, void* d_ws, size_t ws_size,
                              hipStream_t stream) {
    const float* x    = (const float*)d_in[0];   // (16,384,56,56)
    const float* w_dw = (const float*)d_in[1];   // (384,1,3,3)
    const float* w_pw = (const float*)d_in[2];   // (384,384,1,1)
    float* out = (float*)d_out;

    const size_t y_bytes    = (size_t)NN * HW * CH * sizeof(__hip_bfloat16); // 38.5 MB
    const size_t part_bytes = 96 * sizeof(double);

    if (ws_size >= y_bytes + part_bytes) {
        double* part = (double*)((char*)d_ws + y_bytes);
        partial_kernel<<<96, 256, 0, stream>>>(w_pw, part);
        quant_kernel<<<36, 512, 0, stream>>>(w_dw, w_pw, part);
        __hip_bfloat16* yg = (__hip_bfloat16*)d_ws;
        dw_kernel<<<NN * HH * 2, 448, 0, stream>>>(x, yg);
        pw_kernel<<<NN * 28 * 3, 256, 0, stream>>>(yg, out);
    } else if (ws_size >= part_bytes) {
        double* part = (double*)d_ws;
        partial_kernel<<<96, 256, 0, stream>>>(w_pw, part);
        quant_kernel<<<36, 512, 0, stream>>>(w_dw, w_pw, part);
        fused_kernel<<<NN * HH, 512, 0, stream>>>(x, out);
    }
}

// Round 9
// 67.041 us; speedup vs baseline: 1.1765x; 1.1765x over previous
//
#include <hip/hip_runtime.h>
#include <hip/hip_bf16.h>

#define CH 384
#define HH 56
#define WW 56
#define HW (HH*WW)      // 3136 = 28*112
#define NN 16
#define BN 112          // pw pix-tile (3136 = 28*112 exact)
#define BK 64           // pw k-chunk

typedef __attribute__((ext_vector_type(4))) float f32x4;
typedef __attribute__((ext_vector_type(8))) short bf16x8;

// Prepared weights
__device__ float          g_wdw_eff[CH * 9];   // depthwise: u*mx exact fp32, [o][tap]
__device__ __hip_bfloat16 g_wpw_u[CH * CH];    // pointwise: ternary u exact bf16, [co][ci]
__device__ float          g_mx_pw;             // pointwise scale (epilogue multiply)

// ---------- prep stage A: deterministic per-block |w| partial sums ----------
__global__ __launch_bounds__(256) void partial_kernel(const float* __restrict__ wpw,
                                                      double* __restrict__ part) {
    const int t = threadIdx.x;
    const int base = blockIdx.x * 1536;
    double s = 0.0;
    #pragma unroll
    for (int k = 0; k < 6; ++k) s += (double)fabsf(wpw[base + t + k * 256]);
    #pragma unroll
    for (int off = 32; off > 0; off >>= 1) s += __shfl_down(s, off, 64);
    __shared__ double sred[4];
    if ((t & 63) == 0) sred[t >> 6] = s;
    __syncthreads();
    if (t == 0) part[blockIdx.x] = ((sred[0] + sred[1]) + sred[2]) + sred[3];
}

// ---------- prep stage B: finalize scale (in-order, deterministic) + quantize ----------
__global__ __launch_bounds__(512) void quant_kernel(const float* __restrict__ wdw,
                                                    const float* __restrict__ wpw,
                                                    const double* __restrict__ part) {
    const int t = threadIdx.x;
    __shared__ double pl[96];
    __shared__ float s_scale, s_mx;
    if (t < 96) pl[t] = part[t];
    __syncthreads();
    if (t == 0) {
        double tot = 0.0;
        #pragma unroll
        for (int i = 0; i < 96; ++i) tot += pl[i];   // fixed order
        const float mean = (float)(tot / (double)(CH * CH));
        const float mx   = fmaxf(mean, 1e-5f);
        s_mx = mx;
        s_scale = 1.0f / mx;
    }
    __syncthreads();
    const float scale = s_scale;

    const int base = blockIdx.x * 4096 + t * 8;      // 36*512*8 = 147456 exact
    const float4 a = *reinterpret_cast<const float4*>(wpw + base);
    const float4 b = *reinterpret_cast<const float4*>(wpw + base + 4);
    const float vin[8] = {a.x, a.y, a.z, a.w, b.x, b.y, b.z, b.w};
    bf16x8 uo;
    #pragma unroll
    for (int k = 0; k < 8; ++k) {
        float u = rintf(vin[k] * scale);             // jnp.round == RNE
        u = fminf(1.f, fmaxf(-1.f, u));
        __hip_bfloat16 h = __float2bfloat16(u);      // {-1,0,1} exact in bf16
        uo[k] = *reinterpret_cast<short*>(&h);
    }
    *reinterpret_cast<bf16x8*>(g_wpw_u + base) = uo;

    if (blockIdx.x == 0) {
        if (t == 0) g_mx_pw = s_mx;
        if (t < CH) {
            const float* w = wdw + t * 9;
            float asum = 0.f;
            #pragma unroll
            for (int k = 0; k < 9; ++k) asum += fabsf(w[k]);
            const float mxd = fmaxf(asum / 9.0f, 1e-5f);
            const float scd = 1.0f / mxd;
            #pragma unroll
            for (int k = 0; k < 9; ++k) {
                float u = rintf(w[k] * scd);
                u = fminf(1.f, fmaxf(-1.f, u));
                g_wdw_eff[t * 9 + k] = u * mxd;      // exact product
            }
        }
    }
}

// ---------- kernel 1: depthwise v5 — global_load_lds staged x-slabs ----------
// Block = (n, 4-row band, 32-ci group), 448 thr (7 waves). Stage: 32 ci slabs
// of 6 halo rows x 224B, tight-packed 85 x 16B slots/ci (slot 84 = pad), all
// wave-issues fully contiguous (16 full lines/issue) -> minimal transactions
// (rounds 6-8: gather pattern at 2 lanes/line was transaction-rate bound at
// ~60us). Compute from LDS; Y transposed in LDS (XOR-8 swizzle); full-line dump.
__global__ __launch_bounds__(448, 3) void dw_kernel(const float* __restrict__ x,
                                                    __hip_bfloat16* __restrict__ y) {
    __shared__ __attribute__((aligned(16))) char xs[44032];            // 32ci * 1360B + 512 pad
    __shared__ __attribute__((aligned(16))) __hip_bfloat16 ys[224 * 32]; // 14336B

    const int bid  = blockIdx.x;
    const int orig = (bid & 7) * 336 + (bid >> 3);   // XCD swizzle, 2688 = 8*336
    const int n    = orig / 168;                     // 168 = 12 cig * 14 band
    const int rem  = orig - n * 168;
    const int cig  = rem / 14;
    const int band = rem - cig * 14;
    const int h0   = band * 4;
    const int ci0  = cig * 32;

    const int wv   = threadIdx.x >> 6;
    const int lane = threadIdx.x & 63;

    // ---- stage: 2720 slots (+32 pad) = 43 wave-issues (6/wave + 1 on wave 0) ----
    const float* xg = x + ((size_t)n * CH + ci0) * HW;
    #pragma unroll
    for (int i = 0; i < 7; ++i) {
        if (i == 6 && wv != 0) break;                // wave-uniform
        const int sbase = (i == 6) ? 2688 : (i * 7 + wv) * 64;
        const int s = sbase + lane;
        unsigned ci = (unsigned)(((unsigned long long)s * 50529028ull) >> 32); // s/85
        ci = ci > 31u ? 31u : ci;
        const int b = s - (int)ci * 85;              // 0..84 (84 = pad chunk)
        int r = (b * 18725) >> 18;                   // b/14: 0..6
        const int col = b - 14 * r;                  // 0..13
        r = r > 5 ? 5 : r;
        int xrow = h0 - 1 + r;
        xrow = xrow < 0 ? 0 : (xrow > HH - 1 ? HH - 1 : xrow);
        const float* src = xg + (size_t)ci * HW + xrow * WW + col * 4;
        __builtin_amdgcn_global_load_lds(
            (const __attribute__((address_space(1))) void*)src,
            (__attribute__((address_space(3))) void*)(xs + sbase * 16),
            16, 0, 0);
    }
    __syncthreads();

    // ---- compute: thread = (ci, rp, wc); out rows h0+rp and h0+rp+2, 8 w ----
    const int t  = threadIdx.x;                      // 0..447 = 32ci * 2rp * 7wc
    const int ci = t / 14;
    const int rm = t - ci * 14;
    const int rp = rm / 7;                           // 0..1
    const int wc = rm - rp * 7;                      // 0..6
    const int w0 = wc * 8;

    const float* wdp = g_wdw_eff + (ci0 + ci) * 9;
    float wt[9];
    #pragma unroll
    for (int k = 0; k < 9; ++k) wt[k] = wdp[k];
    const bool mt = (h0 == 0 && rp == 0);            // out-row rp, top tap invalid
    const bool mb = (h0 == 52 && rp == 1);           // out-row rp+2, bottom tap invalid
    float wtop[3], wbot[3];
    #pragma unroll
    for (int d = 0; d < 3; ++d) {
        wtop[d] = mt ? 0.f : wt[d];
        wbot[d] = mb ? 0.f : wt[6 + d];
    }

    // 5-row window: staged rows rp..rp+4
    const char* xb = xs + ci * 1360 + rp * 224 + 32 * wc;
    float xv[5][10];
    #pragma unroll
    for (int rr = 0; rr < 5; ++rr) {
        const char* rowp = xb + rr * 224;
        const f32x4 a = *reinterpret_cast<const f32x4*>(rowp);
        const f32x4 b = *reinterpret_cast<const f32x4*>(rowp + 16);
        const float e0 = (wc > 0) ? *reinterpret_cast<const float*>(rowp - 4) : 0.f;
        float e1 = *reinterpret_cast<const float*>(rowp + 32);
        if (wc == 6) e1 = 0.f;                       // w=56 pad (slot-84 garbage)
        xv[rr][0] = e0;
        xv[rr][1] = a.x; xv[rr][2] = a.y; xv[rr][3] = a.z; xv[rr][4] = a.w;
        xv[rr][5] = b.x; xv[rr][6] = b.y; xv[rr][7] = b.z; xv[rr][8] = b.w;
        xv[rr][9] = e1;
    }

    float acc0[8], acc1[8];
    #pragma unroll
    for (int j = 0; j < 8; ++j) {
        float s0 = 0.f, s1 = 0.f;
        #pragma unroll
        for (int d = 0; d < 3; ++d) {
            s0 += wtop[d]   * xv[0][j + d];          // out row rp:   staged rp..rp+2
            s0 += wt[3 + d] * xv[1][j + d];
            s0 += wt[6 + d] * xv[2][j + d];
            s1 += wt[d]     * xv[2][j + d];          // out row rp+2: staged rp+2..rp+4
            s1 += wt[3 + d] * xv[3][j + d];
            s1 += wbot[d]   * xv[4][j + d];
        }
        acc0[j] = s0; acc1[j] = s1;
    }

    // ---- Y transpose to LDS: [pix][32ci], 8-group XOR swizzle on ci ----
    const int g8 = ci >> 3, c7 = ci & 7;
    #pragma unroll
    for (int j = 0; j < 8; ++j) {
        const int pixA = rp * WW + w0 + j;
        const int pixB = (rp + 2) * WW + w0 + j;
        ys[pixA * 32 + ((g8 ^ ((pixA >> 3) & 3)) << 3) + c7] = __float2bfloat16(acc0[j]);
        ys[pixB * 32 + ((g8 ^ ((pixB >> 3) & 3)) << 3) + c7] = __float2bfloat16(acc1[j]);
    }
    __syncthreads();

    // ---- dump: 896 b128 slots, full-line coalesced global stores ----
    __hip_bfloat16* yb = y + ((size_t)n * HW + (size_t)h0 * WW) * CH + ci0;
    #pragma unroll
    for (int k = 0; k < 2; ++k) {
        const int t2 = t + 448 * k;                  // 0..895
        const int pix = t2 >> 2;
        const int g  = t2 & 3;
        const int sg = g ^ ((pix >> 3) & 3);
        const bf16x8 v = *reinterpret_cast<const bf16x8*>(&ys[pix * 32 + sg * 8]);
        *reinterpret_cast<bf16x8*>(yb + (size_t)pix * CH + g * 8) = v;
    }
}

// ---------- kernel 2: pointwise GEMM, global_load_lds-staged B, dbuf ----------
// (unchanged from rounds 6-8 — out of top-5)
#define STAGE(B, KC) do {                                                         \
    const int _k0 = (KC) * BK;                                                    \
    _Pragma("unroll")                                                             \
    for (int _i = 0; _i < 4; ++_i) {                                              \
        const int _sb = wv * 4 + _i;                                              \
        if (_sb < 14) {                                                           \
            const int _s  = _sb * 64 + lane;                                      \
            const int _p  = _s >> 3;                                              \
            const int _c8 = (_s & 7) ^ (_p & 7);                                  \
            __builtin_amdgcn_global_load_lds(                                     \
                (const __attribute__((address_space(1))) void*)                  \
                    (yb + (size_t)_p * CH + _k0 + _c8 * 8),                       \
                (__attribute__((address_space(3))) void*)                        \
                    (&blds[(B)][0] + _sb * 512),                                  \
                16, 0, 0);                                                        \
        }                                                                         \
    }                                                                             \
} while (0)

#define LOADA(dst, KC) {                                                          \
    dst[0][0] = *reinterpret_cast<const bf16x8*>(ap0 + (KC) * 64);                \
    dst[0][1] = *reinterpret_cast<const bf16x8*>(ap0 + (KC) * 64 + 32);           \
    dst[1][0] = *reinterpret_cast<const bf16x8*>(ap1 + (KC) * 64);                \
    dst[1][1] = *reinterpret_cast<const bf16x8*>(ap1 + (KC) * 64 + 32); }

__global__ __launch_bounds__(256) void pw_kernel(const __hip_bfloat16* __restrict__ y,
                                                 float* __restrict__ out) {
    __shared__ __attribute__((aligned(16))) __hip_bfloat16 blds[2][BN * BK]; // 2x14336 B

    const int bid  = blockIdx.x;
    const int orig = (bid & 7) * 168 + (bid >> 3);   // XCD swizzle, 1344 = 8*168
    const int n  = orig / 84;                        // 84 = 28*3
    const int r  = orig % 84;
    const int pt = r / 3;                            // pix tile 0..27
    const int cb = r % 3;                            // co tile 0..2
    const int wv   = threadIdx.x >> 6;
    const int lane = threadIdx.x & 63;
    const int lr   = lane & 15;
    const int lk   = lane >> 4;

    const __hip_bfloat16* yb = y + ((size_t)n * HW + (size_t)pt * BN) * CH;
    const __hip_bfloat16* ap0 = g_wpw_u + (size_t)(cb * 128 + wv * 32 + lr) * CH + 8 * lk;
    const __hip_bfloat16* ap1 = ap0 + (size_t)16 * CH;

    f32x4 acc[2][7];
    #pragma unroll
    for (int i = 0; i < 2; ++i)
        #pragma unroll
        for (int j = 0; j < 7; ++j) acc[i][j] = (f32x4){0.f, 0.f, 0.f, 0.f};

    bf16x8 areg[2][2][2];                            // [buf][cofrag][kk]
    STAGE(0, 0);
    LOADA(areg[0], 0);
    __syncthreads();                                 // stage(0) + A(0) complete

    #pragma unroll
    for (int kc = 0; kc < 6; ++kc) {
        const int cur = kc & 1;
        if (kc < 5) { STAGE(cur ^ 1, kc + 1); LOADA(areg[cur ^ 1], kc + 1); }
        #pragma unroll
        for (int kk = 0; kk < 2; ++kk) {
            bf16x8 bfr[7];
            #pragma unroll
            for (int j = 0; j < 7; ++j) {
                const int p  = 16 * j + lr;
                const int c8 = (kk * 4 + lk) ^ (p & 7);
                bfr[j] = *reinterpret_cast<const bf16x8*>(&blds[cur][p * 64 + c8 * 8]);
            }
            #pragma unroll
            for (int i = 0; i < 2; ++i)
                #pragma unroll
                for (int j = 0; j < 7; ++j)
                    acc[i][j] = __builtin_amdgcn_mfma_f32_16x16x32_bf16(
                        areg[cur][i][kk], bfr[j], acc[i][j], 0, 0, 0);
        }
        __syncthreads();   // drains next-chunk stage (vmcnt0) + guards dbuf reuse
    }

    // epilogue: D col(lane&15)=pix, row(lk*4+reg)=co
    const float s = g_mx_pw;
    float* ob = out + (size_t)n * CH * HW + (size_t)pt * BN;
    #pragma unroll
    for (int i = 0; i < 2; ++i) {
        const int co0 = cb * 128 + wv * 32 + i * 16 + lk * 4;
        #pragma unroll
        for (int j = 0; j < 7; ++j) {
            const int px = 16 * j + lr;
            #pragma unroll
            for (int rr = 0; rr < 4; ++rr)
                ob[(size_t)(co0 + rr) * HW + px] = acc[i][j][rr] * s;
        }
    }
}

// ---------- fallback: fused kernel (only if ws too small) ----------
__global__ __launch_bounds__(512) void fused_kernel(const float* __restrict__ x,
                                                    float* __restrict__ out) {
    __shared__ __attribute__((aligned(16))) __hip_bfloat16 ylds[64 * CH];
    const int bid  = blockIdx.x;
    const int orig = (bid & 7) * 112 + (bid >> 3);
    const int n = orig / HH, h = orig % HH;
    const float* xn = x + (size_t)n * CH * HW;

    for (int u = threadIdx.x; u < CH * 7; u += 512) {
        const int ci = u / 7;
        const int wc = u % 7;
        const int w0 = wc * 8;
        const float* xp = xn + (size_t)ci * HW;
        const float* wd = g_wdw_eff + ci * 9;
        float acc[8] = {0.f, 0.f, 0.f, 0.f, 0.f, 0.f, 0.f, 0.f};
        #pragma unroll
        for (int dy = -1; dy <= 1; ++dy) {
            const int hh = h + dy;
            if (hh < 0 || hh >= HH) continue;
            const float* row = xp + hh * WW;
            const float4 va = *reinterpret_cast<const float4*>(row + w0);
            const float4 vb = *reinterpret_cast<const float4*>(row + w0 + 4);
            const float left  = (w0 > 0)      ? row[w0 - 1] : 0.f;
            const float right = (w0 + 8 < WW) ? row[w0 + 8] : 0.f;
            const float xv[10] = {left, va.x, va.y, va.z, va.w,
                                  vb.x, vb.y, vb.z, vb.w, right};
            #pragma unroll
            for (int dx = 0; dx < 3; ++dx) {
                const float wvv = wd[(dy + 1) * 3 + dx];
                #pragma unroll
                for (int j = 0; j < 8; ++j) acc[j] += xv[j + dx] * wvv;
            }
        }
        #pragma unroll
        for (int j = 0; j < 8; ++j)
            ylds[(w0 + j) * CH + (ci ^ ((j ^ wc) << 3))] = __float2bfloat16(acc[j]);
    }
    __syncthreads();

    const int wv   = threadIdx.x >> 6;
    const int lane = threadIdx.x & 63;
    const int lr   = lane & 15;
    const int lk   = lane >> 4;
    f32x4 acc[3][4];
    #pragma unroll
    for (int i = 0; i < 3; ++i)
        #pragma unroll
        for (int j = 0; j < 4; ++j) acc[i][j] = (f32x4){0.f, 0.f, 0.f, 0.f};
    const __hip_bfloat16* abase = g_wpw_u + (size_t)(wv * 16 + lr) * CH + 8 * lk;
    for (int k0 = 0; k0 < CH; k0 += 32) {
        bf16x8 bfr[4];
        #pragma unroll
        for (int j = 0; j < 4; ++j) {
            const int row = 16 * j + lr;
            const int sw  = ((row & 7) ^ ((row >> 3) & 7)) << 3;
            bfr[j] = *reinterpret_cast<const bf16x8*>(&ylds[row * CH + ((k0 + 8 * lk) ^ sw)]);
        }
        #pragma unroll
        for (int i = 0; i < 3; ++i) {
            const bf16x8 afr = *reinterpret_cast<const bf16x8*>(abase + (size_t)(i * 128) * CH + k0);
            #pragma unroll
            for (int j = 0; j < 4; ++j)
                acc[i][j] = __builtin_amdgcn_mfma_f32_16x16x32_bf16(afr, bfr[j], acc[i][j], 0, 0, 0);
        }
    }
    const float s = g_mx_pw;
    float* obase = out + (size_t)n * CH * HW + (size_t)h * WW;
    #pragma unroll
    for (int j = 0; j < 4; ++j) {
        const int pix = 16 * j + lr;
        if (pix >= WW) continue;
        #pragma unroll
        for (int i = 0; i < 3; ++i) {
            const int co0 = (wv + 8 * i) * 16 + lk * 4;
            #pragma unroll
            for (int rr = 0; rr < 4; ++rr)
                obase[(size_t)(co0 + rr) * HW + pix] = acc[i][j][rr] * s;
        }
    }
}

extern "C" void kernel_launch(void* const* d_in, const int* in_sizes, int n_in,
                              void* d_out, int out_size, void* d_ws, size_t ws_size,
                              hipStream_t stream) {
    const float* x    = (const float*)d_in[0];   // (16,384,56,56)
    const float* w_dw = (const float*)d_in[1];   // (384,1,3,3)
    const float* w_pw = (const float*)d_in[2];   // (384,384,1,1)
    float* out = (float*)d_out;

    const size_t y_bytes    = (size_t)NN * HW * CH * sizeof(__hip_bfloat16); // 38.5 MB
    const size_t part_bytes = 96 * sizeof(double);

    if (ws_size >= y_bytes + part_bytes) {
        double* part = (double*)((char*)d_ws + y_bytes);
        partial_kernel<<<96, 256, 0, stream>>>(w_pw, part);
        quant_kernel<<<36, 512, 0, stream>>>(w_dw, w_pw, part);
        __hip_bfloat16* yg = (__hip_bfloat16*)d_ws;
        dw_kernel<<<NN * 14 * 12, 448, 0, stream>>>(x, yg);
        pw_kernel<<<NN * 28 * 3, 256, 0, stream>>>(yg, out);
    } else if (ws_size >= part_bytes) {
        double* part = (double*)d_ws;
        partial_kernel<<<96, 256, 0, stream>>>(w_pw, part);
        quant_kernel<<<36, 512, 0, stream>>>(w_dw, w_pw, part);
        fused_kernel<<<NN * HH, 512, 0, stream>>>(x, out);
    }
}